// Round 15
// baseline (157.986 us; speedup 1.0000x reference)
//
#include <hip/hip_runtime.h>

#define D 128
#define STRIDE 6144  // max edges per 256-node bucket (mean 4082, sd 64)

typedef _Float16 f16;
typedef f16 f16x2 __attribute__((ext_vector_type(2)));
typedef f16 f16x8 __attribute__((ext_vector_type(8)));
typedef float f32x4 __attribute__((ext_vector_type(4)));

__device__ inline f16x2 u2h(unsigned u) { return __builtin_bit_cast(f16x2, u); }
__device__ inline unsigned h2u(f16x2 h) { return __builtin_bit_cast(unsigned, h); }

__device__ inline float dot2(unsigned a, unsigned b, float c) {
#if __has_builtin(__builtin_amdgcn_fdot2)
    return __builtin_amdgcn_fdot2(u2h(a), u2h(b), c, false);
#else
    f16x2 x = u2h(a), y = u2h(b);
    return c + (float)x.x * (float)y.x + (float)x.y * (float)y.y;
#endif
}

// ---------------- weight prep (one-time, 4 blocks): W fp32 -> transposed f16, swizzled ----------------
// f16 index for (col c, k): c*128 + ((k>>3) ^ (c&15))*8 + (k&7)
__global__ void wt_prep4(const float* __restrict__ W0, const float* __restrict__ W1,
                         const float* __restrict__ W2, const float* __restrict__ W3,
                         f16* __restrict__ Wt) {
    const float* W = (blockIdx.x == 0) ? W0 : (blockIdx.x == 1) ? W1 : (blockIdx.x == 2) ? W2 : W3;
    f16* o = Wt + (size_t)blockIdx.x * D * D;
    int t = threadIdx.x;
#pragma unroll
    for (int i = 0; i < 16; ++i) {
        int f = t + i * 256;
        int k = f >> 5, c4 = f & 31;
        float4 v = *(const float4*)(W + k * D + 4 * c4);
        float vv[4] = {v.x, v.y, v.z, v.w};
#pragma unroll
        for (int e = 0; e < 4; ++e) {
            int c = 4 * c4 + e;
            o[c * D + (((k >> 3) ^ (c & 15)) << 3) + (k & 7)] = (f16)vv[e];
        }
    }
}

// ---- shared GEMM pieces ----
__device__ inline void stage_w(const f16* __restrict__ Wt, f16* Wl, int t) {
#pragma unroll
    for (int i = 0; i < 8; ++i) ((uint4*)Wl)[t + i * 256] = ((const uint4*)Wt)[t + i * 256];
}

__device__ inline void stage_x_f32(const float* __restrict__ x, f16* xs, int r0, int nrows, int t) {
#pragma unroll
    for (int i = 0; i < 8; ++i) {
        int f = t + i * 256;
        int r = f >> 5, c4 = f & 31;
        int gr = r0 + r;
        float4 v = {0.f, 0.f, 0.f, 0.f};
        if (gr < nrows) v = *(const float4*)(x + (size_t)gr * D + 4 * c4);
        unsigned lo = h2u((f16x2){(f16)v.x, (f16)v.y});
        unsigned hi = h2u((f16x2){(f16)v.z, (f16)v.w});
        *(uint2*)(xs + r * D + (((c4 >> 1) ^ (r & 15)) << 3) + (c4 & 1) * 4) = (uint2){lo, hi};
    }
}

__device__ inline void mfma_core(const f16* xs, const f16* Wl, f32x4 acc[8], int lane, int w) {
    int lr = lane & 15, g = lane >> 4;
    int arow = 16 * w + lr;
#pragma unroll
    for (int kc = 0; kc < 4; ++kc) {
        int slot = kc * 4 + g;
        f16x8 af = *(const f16x8*)(xs + arow * D + ((slot ^ (arow & 15)) << 3));
#pragma unroll
        for (int ct = 0; ct < 8; ++ct) {
            int col = ct * 16 + lr;
            f16x8 bf = *(const f16x8*)(Wl + col * D + ((slot ^ (col & 15)) << 3));
            acc[ct] = __builtin_amdgcn_mfma_f32_16x16x32_f16(af, bf, acc[ct], 0, 0, 0);
        }
    }
}

// ---- fused front-end: [bucket_split | gemm_q | gemm_kv] by blockIdx range ----
__global__ __launch_bounds__(256) void fused_front(
    const float* __restrict__ x_node, const float* __restrict__ x_edge,
    const int* __restrict__ src, const int* __restrict__ dst,
    const f16* __restrict__ Wt,
    const float* __restrict__ bq, const float* __restrict__ bk, const float* __restrict__ bv,
    f16* __restrict__ Qh, f16* __restrict__ KVh,
    int* __restrict__ bucket_cnt, unsigned* __restrict__ temp,
    int N, int M, int E, int nsp, int nq, float qscale) {
    __shared__ __align__(16) f16 Wl[D * D];     // 32 KB
    __shared__ __align__(16) f16 xs[64 * D];    // 16 KB
    int t = threadIdx.x;
    int bid = blockIdx.x;

    if (bid < nsp) {
        // ---- bucket split: LDS bucket-sort, coalesced run-writes to temp ----
        int* hist = (int*)Wl;
        int* lex = hist + 256;
        int* gbase = lex + 256;
        int* lcur = gbase + 256;
        int* wsum = lcur + 256;
        int* sorted = wsum + 16;
        unsigned char* sbyte = (unsigned char*)xs;
        hist[t] = 0;
        lcur[t] = 0;
        __syncthreads();
        int base0 = bid * 4096;
        int lim = E - base0; if (lim > 4096) lim = 4096;
        for (int i = t; i < lim; i += 256) atomicAdd(&hist[src[base0 + i] >> 8], 1);
        __syncthreads();
        int v = hist[t];
        int inc = v;
#pragma unroll
        for (int m = 1; m < 64; m <<= 1) {
            int u = __shfl_up(inc, m);
            if ((t & 63) >= m) inc += u;
        }
        if ((t & 63) == 63) wsum[t >> 6] = inc;
        __syncthreads();
        int add = 0;
#pragma unroll
        for (int w = 0; w < 4; ++w)
            if (w < (t >> 6)) add += wsum[w];
        lex[t] = add + inc - v;
        if (v) gbase[t] = atomicAdd(&bucket_cnt[t], v);
        __syncthreads();
        for (int i = t; i < lim; i += 256) {
            int s = src[base0 + i];
            int bk2 = s >> 8;
            int lp = atomicAdd(&lcur[bk2], 1);
            int sp = lex[bk2] + lp;
            sorted[sp] = ((s & 255) << 24) | dst[base0 + i];
            sbyte[sp] = (unsigned char)bk2;
        }
        __syncthreads();
        for (int i = t; i < lim; i += 256) {
            int bk2 = sbyte[i];
            int gp = gbase[bk2] + (i - lex[bk2]);
            if (gp < STRIDE) temp[(size_t)bk2 * STRIDE + gp] = (unsigned)sorted[i];
        }
    } else if (bid < nsp + nq) {
        // ---- Q GEMM: Qh = (x_node@Wq + bq)*qscale, f16 row-major ----
        int r0 = (bid - nsp) * 64;
        stage_w(Wt, Wl, t);
        stage_x_f32(x_node, xs, r0, N, t);
        __syncthreads();
        int lane = t & 63, w = t >> 6;
        f32x4 acc[8];
#pragma unroll
        for (int i = 0; i < 8; ++i) acc[i] = (f32x4){0.f, 0.f, 0.f, 0.f};
        mfma_core(xs, Wl, acc, lane, w);
        __syncthreads();
        int lr = lane & 15, g = lane >> 4;
#pragma unroll
        for (int ct = 0; ct < 8; ++ct) {
            int col = ct * 16 + lr;
            float bias = bq[col];
#pragma unroll
            for (int rg = 0; rg < 4; ++rg) {
                int row = 16 * w + 4 * g + rg;
                xs[row * D + (((col >> 3) ^ (row & 15)) << 3) + (col & 7)] =
                    (f16)((acc[ct][rg] + bias) * qscale);
            }
        }
        __syncthreads();
#pragma unroll
        for (int i = 0; i < 4; ++i) {
            int f = t + i * 256;
            int r = f >> 4, c8 = f & 15;
            if (r0 + r < N) {
                uint4 v = *(const uint4*)(xs + r * D + ((c8 ^ (r & 15)) << 3));
                *(uint4*)(Qh + (size_t)(r0 + r) * D + 8 * c8) = v;
            }
        }
    } else {
        // ---- K|V GEMM: KVh row = 32 chunks of (k[4]|v[4]) f16 ----
        int r0 = (bid - nsp - nq) * 64;
        stage_w(Wt + D * D, Wl, t);
        stage_x_f32(x_edge, xs, r0, M, t);
        __syncthreads();
        int lane = t & 63, w = t >> 6;
        f32x4 accK[8], accV[8];
#pragma unroll
        for (int i = 0; i < 8; ++i) accK[i] = accV[i] = (f32x4){0.f, 0.f, 0.f, 0.f};
        mfma_core(xs, Wl, accK, lane, w);
        __syncthreads();
        stage_w(Wt + 2 * D * D, Wl, t);
        __syncthreads();
        mfma_core(xs, Wl, accV, lane, w);
        __syncthreads();
        int lr = lane & 15, g = lane >> 4;
#pragma unroll
        for (int ct = 0; ct < 8; ++ct) {
            int col = ct * 16 + lr;
            float bbk = bk[col], bbv = bv[col];
            int s = col >> 2, wk = col & 3;
#pragma unroll
            for (int rg = 0; rg < 4; ++rg) {
                int row = 16 * w + 4 * g + rg;
                f16* base = Wl + row * 256 + ((s ^ (row & 15)) << 3);
                base[wk] = (f16)(accK[ct][rg] + bbk);
                base[4 + wk] = (f16)(accV[ct][rg] + bbv);
            }
        }
        __syncthreads();
#pragma unroll
        for (int i = 0; i < 8; ++i) {
            int f = t + i * 256;
            int r = f >> 5, c8 = f & 31;
            if (r0 + r < M) {
                uint4 v = *(const uint4*)(Wl + r * 256 + ((c8 ^ (r & 15)) << 3));
                *(uint4*)(KVh + (size_t)(r0 + r) * 256 + 8 * c8) = v;
            }
        }
    }
}

// ---- bucket scatter: self-scans bucket counts, writes off[] + csr; per-node dst-sort ----
__global__ __launch_bounds__(256) void bucket_scatter(const unsigned* __restrict__ temp,
                                                      const int* __restrict__ bucket_cnt,
                                                      int* __restrict__ off,
                                                      int* __restrict__ csr_dst,
                                                      int N, int E, int NBUK) {
    __shared__ int nh[256], cur[256], wsum[4], sc_ex[256];
    __shared__ int lds_dst[STRIDE];
    int b = blockIdx.x, t = threadIdx.x;
    int bc = (t < NBUK) ? bucket_cnt[t] : 0;
    {
        int inc = bc;
#pragma unroll
        for (int m = 1; m < 64; m <<= 1) {
            int u = __shfl_up(inc, m);
            if ((t & 63) >= m) inc += u;
        }
        if ((t & 63) == 63) wsum[t >> 6] = inc;
        __syncthreads();
        int add = 0;
#pragma unroll
        for (int w = 0; w < 4; ++w)
            if (w < (t >> 6)) add += wsum[w];
        sc_ex[t] = add + inc - bc;
        nh[t] = 0;
    }
    __syncthreads();
    int bo = sc_ex[b];
    int cnt = bucket_cnt[b];
    if (cnt > STRIDE) cnt = STRIDE;
    const unsigned* tb = temp + (size_t)b * STRIDE;
    for (int i = t; i < cnt; i += 256) atomicAdd(&nh[tb[i] >> 24], 1);
    __syncthreads();
    int v = nh[t];
    int inc = v;
#pragma unroll
    for (int m = 1; m < 64; m <<= 1) {
        int u = __shfl_up(inc, m);
        if ((t & 63) >= m) inc += u;
    }
    if ((t & 63) == 63) wsum[t >> 6] = inc;
    __syncthreads();
    int add = 0;
#pragma unroll
    for (int w = 0; w < 4; ++w)
        if (w < (t >> 6)) add += wsum[w];
    int ex = add + inc - v;
    cur[t] = ex;
    int node = (b << 8) + t;
    if (node < N) off[node] = bo + ex;
    if (b == 0 && t == 0) off[N] = E;
    __syncthreads();
    for (int i = t; i < cnt; i += 256) {
        unsigned it = tb[i];
        int lpos = atomicAdd(&cur[it >> 24], 1);
        lds_dst[lpos] = (int)(it & 0xFFFFFFu);
    }
    __syncthreads();
    // per-node insertion sort by dst: concurrent waves then walk ascending dst
    // in near-lockstep -> KV access window fits L2 (moving-window locality).
    for (int i = ex + 1; i < ex + v; ++i) {
        int key = lds_dst[i];
        int k2 = i - 1;
        while (k2 >= ex && lds_dst[k2] > key) {
            lds_dst[k2 + 1] = lds_dst[k2];
            --k2;
        }
        lds_dst[k2 + 1] = key;
    }
    __syncthreads();
    for (int i = t; i < cnt; i += 256) csr_dst[bo + i] = lds_dst[i];
}

// ---- fused per-node attention (R9-verified): 8 lanes/edge, 8 edges in flight ----
// Lane j owns dims 16j..16j+15; head = 32 dims = lane pair, reduce = shfl_xor(s,1) only.
__global__ __launch_bounds__(256) void node_attn4(const f16* __restrict__ Qh,
                                                  const f16* __restrict__ KVh,
                                                  const int* __restrict__ off,
                                                  const int* __restrict__ csr,
                                                  f16* __restrict__ aggh, int N) {
    int wid = (int)((blockIdx.x * (size_t)blockDim.x + threadIdx.x) >> 6);
    int lane = threadIdx.x & 63;
    if (wid >= N) return;
    int j = lane & 7, g = lane >> 3;
    const f16* qp = Qh + (size_t)wid * D + 16 * j;
    uint4 qA = *(const uint4*)qp;
    uint4 qB = *(const uint4*)(qp + 8);
    int beg = off[wid], end = off[wid + 1];
    float z = 0.f;
    f16x2 a0 = {0, 0}, a1 = {0, 0}, a2 = {0, 0}, a3 = {0, 0};
    f16x2 a4 = {0, 0}, a5 = {0, 0}, a6 = {0, 0}, a7 = {0, 0};
    if (beg < end) {
        int pe = beg + g;
        int d0 = csr[(pe < end) ? pe : end - 1];
        const f16* r = KVh + (size_t)d0 * 256 + 32 * j;
        uint4 A0 = *(const uint4*)r;
        uint4 A1 = *(const uint4*)(r + 8);
        uint4 A2 = *(const uint4*)(r + 16);
        uint4 A3 = *(const uint4*)(r + 24);
        for (int p = beg; p < end; p += 8) {
            int pn = p + 8 + g;
            int dn = csr[(pn < end) ? pn : end - 1];
            const f16* rn = KVh + (size_t)dn * 256 + 32 * j;
            uint4 B0 = *(const uint4*)rn;
            uint4 B1 = *(const uint4*)(rn + 8);
            uint4 B2 = *(const uint4*)(rn + 16);
            uint4 B3 = *(const uint4*)(rn + 24);
            bool valid = (p + g) < end;
            float s = dot2(A0.x, qA.x, 0.f);
            s = dot2(A0.y, qA.y, s);
            s = dot2(A1.x, qA.z, s);
            s = dot2(A1.y, qA.w, s);
            s = dot2(A2.x, qB.x, s);
            s = dot2(A2.y, qB.y, s);
            s = dot2(A3.x, qB.z, s);
            s = dot2(A3.y, qB.w, s);
            s += __shfl_xor(s, 1);   // lane pair = 32 dims = ONE head
            float eh = valid ? __expf(s) : 0.f;
            z += eh;
            f16 e16 = (f16)eh;
            f16x2 e2 = {e16, e16};
            a0 += e2 * u2h(A0.z); a1 += e2 * u2h(A0.w);
            a2 += e2 * u2h(A1.z); a3 += e2 * u2h(A1.w);
            a4 += e2 * u2h(A2.z); a5 += e2 * u2h(A2.w);
            a6 += e2 * u2h(A3.z); a7 += e2 * u2h(A3.w);
            A0 = B0; A1 = B1; A2 = B2; A3 = B3;
        }
    }
#pragma unroll
    for (int m = 8; m < 64; m <<= 1) {
        z += __shfl_xor(z, m);
        a0 += u2h(__shfl_xor((int)h2u(a0), m));
        a1 += u2h(__shfl_xor((int)h2u(a1), m));
        a2 += u2h(__shfl_xor((int)h2u(a2), m));
        a3 += u2h(__shfl_xor((int)h2u(a3), m));
        a4 += u2h(__shfl_xor((int)h2u(a4), m));
        a5 += u2h(__shfl_xor((int)h2u(a5), m));
        a6 += u2h(__shfl_xor((int)h2u(a6), m));
        a7 += u2h(__shfl_xor((int)h2u(a7), m));
    }
    if (g == 0) {
        float inv = (end > beg) ? 1.f / z : 0.f;
        uint4 o0, o1;
        o0.x = h2u((f16x2){(f16)((float)a0.x * inv), (f16)((float)a0.y * inv)});
        o0.y = h2u((f16x2){(f16)((float)a1.x * inv), (f16)((float)a1.y * inv)});
        o0.z = h2u((f16x2){(f16)((float)a2.x * inv), (f16)((float)a2.y * inv)});
        o0.w = h2u((f16x2){(f16)((float)a3.x * inv), (f16)((float)a3.y * inv)});
        o1.x = h2u((f16x2){(f16)((float)a4.x * inv), (f16)((float)a4.y * inv)});
        o1.y = h2u((f16x2){(f16)((float)a5.x * inv), (f16)((float)a5.y * inv)});
        o1.z = h2u((f16x2){(f16)((float)a6.x * inv), (f16)((float)a6.y * inv)});
        o1.w = h2u((f16x2){(f16)((float)a7.x * inv), (f16)((float)a7.y * inv)});
        f16* op = aggh + (size_t)wid * D + 16 * j;
        *(uint4*)op = o0;
        *(uint4*)(op + 8) = o1;
    }
}

// ---- out GEMM: d_out = aggh(f16) @ Wo + bo + x_node, fp32 out ----
__global__ __launch_bounds__(256) void gemm_o(const f16* __restrict__ aggh,
                                              const f16* __restrict__ Wt,
                                              const float* __restrict__ b,
                                              const float* __restrict__ resid,
                                              float* __restrict__ y, int nrows) {
    __shared__ __align__(16) f16 Wl[D * D];
    __shared__ __align__(16) f16 xs[64 * D];
    int t = threadIdx.x;
    int r0 = blockIdx.x * 64;
    stage_w(Wt, Wl, t);
#pragma unroll
    for (int i = 0; i < 4; ++i) {
        int f = t + i * 256;
        int r = f >> 4, c8 = f & 15;
        int gr = r0 + r;
        uint4 v = {0u, 0u, 0u, 0u};
        if (gr < nrows) v = *(const uint4*)(aggh + (size_t)gr * D + 8 * c8);
        *(uint4*)(xs + r * D + ((c8 ^ (r & 15)) << 3)) = v;
    }
    __syncthreads();
    int lane = t & 63, w = t >> 6;
    f32x4 acc[8];
#pragma unroll
    for (int i = 0; i < 8; ++i) acc[i] = (f32x4){0.f, 0.f, 0.f, 0.f};
    mfma_core(xs, Wl, acc, lane, w);
    __syncthreads();
    float* Tf = (float*)Wl;
    int lr = lane & 15, g = lane >> 4;
#pragma unroll
    for (int ct = 0; ct < 8; ++ct) {
        int col = ct * 16 + lr;
        float bias = b[col];
        int s = col >> 2, wk = col & 3;
#pragma unroll
        for (int rg = 0; rg < 4; ++rg) {
            int row = 16 * w + 4 * g + rg;
            Tf[row * D + ((s ^ (row & 15)) << 2) + wk] = acc[ct][rg] + bias;
        }
    }
    __syncthreads();
#pragma unroll
    for (int i = 0; i < 8; ++i) {
        int f = t + i * 256;
        int r = f >> 5, c4 = f & 31;
        int gr = r0 + r;
        if (gr < nrows) {
            float4 v = *(const float4*)(Tf + r * D + ((c4 ^ (r & 15)) << 2));
            float4 rv = *(const float4*)(resid + (size_t)gr * D + 4 * c4);
            v.x += rv.x; v.y += rv.y; v.z += rv.z; v.w += rv.w;
            *(float4*)(y + (size_t)gr * D + 4 * c4) = v;
        }
    }
}

extern "C" void kernel_launch(void* const* d_in, const int* in_sizes, int n_in,
                              void* d_out, int out_size, void* d_ws, size_t ws_size,
                              hipStream_t stream) {
    const float* x_node = (const float*)d_in[0];
    const float* x_edge = (const float*)d_in[1];
    const int* src = (const int*)d_in[2];
    const int* dst = (const int*)d_in[3];
    const float* Wq = (const float*)d_in[4];
    const float* bq = (const float*)d_in[5];
    const float* Wk = (const float*)d_in[6];
    const float* bk = (const float*)d_in[7];
    const float* Wv = (const float*)d_in[8];
    const float* bv = (const float*)d_in[9];
    const float* Wo = (const float*)d_in[10];
    const float* bo = (const float*)d_in[11];

    int N = in_sizes[0] / D;   // 50000
    int M = in_sizes[1] / D;   // 20000
    int E = in_sizes[2];       // 800000
    int NBUK = (N + 255) >> 8; // 196

    char* p = (char*)d_ws;
    auto alloc = [&](size_t bytes) -> char* {
        char* r = p;
        p += (bytes + 15) & ~(size_t)15;
        return r;
    };
    f16* Wt = (f16*)alloc((size_t)4 * D * D * 2);      // q,k,v,o swizzled images
    f16* Qh = (f16*)alloc((size_t)N * D * 2);
    f16* KVh = (f16*)alloc((size_t)M * 256 * 2);
    f16* aggh = (f16*)alloc((size_t)N * D * 2);
    int* bucket_cnt = (int*)alloc(256 * 4);
    int* off = (int*)alloc((size_t)(N + 1) * 4);
    unsigned* temp = (unsigned*)alloc((size_t)NBUK * STRIDE * 4);
    int* csr_dst = (int*)alloc((size_t)E * 4);
    float* out = (float*)d_out;

    hipMemsetAsync(bucket_cnt, 0, 256 * 4, stream);

    wt_prep4<<<4, 256, 0, stream>>>(Wq, Wk, Wv, Wo, Wt);

    int nq = (N + 63) / 64;      // 782
    int nkv = (M + 63) / 64;     // 313
    int nsp = (E + 4095) / 4096; // 196
    fused_front<<<nsp + nq + nkv, 256, 0, stream>>>(x_node, x_edge, src, dst, Wt,
                                                    bq, bk, bv, Qh, KVh,
                                                    bucket_cnt, temp,
                                                    N, M, E, nsp, nq, 0.17677669529663687f);

    bucket_scatter<<<NBUK, 256, 0, stream>>>(temp, bucket_cnt, off, csr_dst, N, E, NBUK);

    int ablk = (int)(((size_t)N * 64 + 255) / 256);
    node_attn4<<<ablk, 256, 0, stream>>>(Qh, KVh, off, csr_dst, aggh, N);

    gemm_o<<<(N + 63) / 64, 256, 0, stream>>>(aggh, Wt + 3 * D * D, bo, x_node, out, N);
}

// Round 16
// 114.038 us; speedup vs baseline: 1.3854x; 1.3854x over previous
//
#include <hip/hip_runtime.h>

#define D 128
#define STRIDE 6144  // max edges per 256-node bucket (mean 4082, sd 64)

typedef _Float16 f16;
typedef f16 f16x2 __attribute__((ext_vector_type(2)));
typedef f16 f16x8 __attribute__((ext_vector_type(8)));
typedef float f32x4 __attribute__((ext_vector_type(4)));

__device__ inline f16x2 u2h(unsigned u) { return __builtin_bit_cast(f16x2, u); }
__device__ inline unsigned h2u(f16x2 h) { return __builtin_bit_cast(unsigned, h); }

__device__ inline float dot2(unsigned a, unsigned b, float c) {
#if __has_builtin(__builtin_amdgcn_fdot2)
    return __builtin_amdgcn_fdot2(u2h(a), u2h(b), c, false);
#else
    f16x2 x = u2h(a), y = u2h(b);
    return c + (float)x.x * (float)y.x + (float)x.y * (float)y.y;
#endif
}

// ---------------- weight prep (one-time, 4 blocks): W fp32 -> transposed f16, swizzled ----------------
// f16 index for (col c, k): c*128 + ((k>>3) ^ (c&15))*8 + (k&7)
__global__ void wt_prep4(const float* __restrict__ W0, const float* __restrict__ W1,
                         const float* __restrict__ W2, const float* __restrict__ W3,
                         f16* __restrict__ Wt) {
    const float* W = (blockIdx.x == 0) ? W0 : (blockIdx.x == 1) ? W1 : (blockIdx.x == 2) ? W2 : W3;
    f16* o = Wt + (size_t)blockIdx.x * D * D;
    int t = threadIdx.x;
#pragma unroll
    for (int i = 0; i < 16; ++i) {
        int f = t + i * 256;
        int k = f >> 5, c4 = f & 31;
        float4 v = *(const float4*)(W + k * D + 4 * c4);
        float vv[4] = {v.x, v.y, v.z, v.w};
#pragma unroll
        for (int e = 0; e < 4; ++e) {
            int c = 4 * c4 + e;
            o[c * D + (((k >> 3) ^ (c & 15)) << 3) + (k & 7)] = (f16)vv[e];
        }
    }
}

// ---- shared GEMM pieces ----
__device__ inline void stage_w(const f16* __restrict__ Wt, f16* Wl, int t) {
#pragma unroll
    for (int i = 0; i < 8; ++i) ((uint4*)Wl)[t + i * 256] = ((const uint4*)Wt)[t + i * 256];
}

// A-fragments direct from global fp32 row (no LDS): a[kc] = k-chunk (kc*4+g) of row gr.
__device__ inline void load_a_f32(const float* __restrict__ x, int gr, int nrows, int g,
                                  f16x8 a[4]) {
#pragma unroll
    for (int kc = 0; kc < 4; ++kc) {
        float4 v0 = {0.f, 0.f, 0.f, 0.f}, v1 = {0.f, 0.f, 0.f, 0.f};
        if (gr < nrows) {
            const float* xr = x + (size_t)gr * D + (kc * 4 + g) * 8;
            v0 = *(const float4*)xr;
            v1 = *(const float4*)(xr + 4);
        }
        f16x8 af;
        af[0] = (f16)v0.x; af[1] = (f16)v0.y; af[2] = (f16)v0.z; af[3] = (f16)v0.w;
        af[4] = (f16)v1.x; af[5] = (f16)v1.y; af[6] = (f16)v1.z; af[7] = (f16)v1.w;
        a[kc] = af;
    }
}

// MFMA with register A-fragments, B from swizzled LDS W image.
__device__ inline void mfma_ra(const f16x8 a[4], const f16* Wl, f32x4 acc[8], int lane) {
    int lr = lane & 15, g = lane >> 4;
#pragma unroll
    for (int kc = 0; kc < 4; ++kc) {
        int slot = kc * 4 + g;
#pragma unroll
        for (int ct = 0; ct < 8; ++ct) {
            int col = ct * 16 + lr;
            f16x8 bf = *(const f16x8*)(Wl + col * D + ((slot ^ (col & 15)) << 3));
            acc[ct] = __builtin_amdgcn_mfma_f32_16x16x32_f16(a[kc], bf, acc[ct], 0, 0, 0);
        }
    }
}

// ---- fused front-end: [bucket_split | gemm_q | gemm_kv] by blockIdx range ----
// LDS = 32 KB (W image only); A-fragments loaded direct from global.
__global__ __launch_bounds__(256) void fused_front(
    const float* __restrict__ x_node, const float* __restrict__ x_edge,
    const int* __restrict__ src, const int* __restrict__ dst,
    const f16* __restrict__ Wt,
    const float* __restrict__ bq, const float* __restrict__ bk, const float* __restrict__ bv,
    f16* __restrict__ Qh, f16* __restrict__ KVh,
    int* __restrict__ bucket_cnt, unsigned* __restrict__ temp,
    int N, int M, int E, int nsp, int nq, float qscale) {
    __shared__ __align__(16) f16 Wl[D * D];     // 32 KB (also split scratch / out tiles)
    int t = threadIdx.x;
    int bid = blockIdx.x;

    if (bid < nsp) {
        // ---- bucket split: LDS bucket-sort, coalesced run-writes to temp ----
        int* hist = (int*)Wl;                 // 256
        int* lex = hist + 256;                // 256
        int* gbase = lex + 256;               // 256
        int* lcur = gbase + 256;              // 256
        int* wsum = lcur + 256;               // 16
        int* sorted = wsum + 16;              // 4096 ints
        unsigned char* sbyte = (unsigned char*)(sorted + 4096);  // 4096 B  (24.6 KB total)
        hist[t] = 0;
        lcur[t] = 0;
        __syncthreads();
        int base0 = bid * 4096;
        int lim = E - base0; if (lim > 4096) lim = 4096;
        for (int i = t; i < lim; i += 256) atomicAdd(&hist[src[base0 + i] >> 8], 1);
        __syncthreads();
        int v = hist[t];
        int inc = v;
#pragma unroll
        for (int m = 1; m < 64; m <<= 1) {
            int u = __shfl_up(inc, m);
            if ((t & 63) >= m) inc += u;
        }
        if ((t & 63) == 63) wsum[t >> 6] = inc;
        __syncthreads();
        int add = 0;
#pragma unroll
        for (int w = 0; w < 4; ++w)
            if (w < (t >> 6)) add += wsum[w];
        lex[t] = add + inc - v;
        if (v) gbase[t] = atomicAdd(&bucket_cnt[t], v);
        __syncthreads();
        for (int i = t; i < lim; i += 256) {
            int s = src[base0 + i];
            int bk2 = s >> 8;
            int lp = atomicAdd(&lcur[bk2], 1);
            int sp = lex[bk2] + lp;
            sorted[sp] = ((s & 255) << 24) | dst[base0 + i];
            sbyte[sp] = (unsigned char)bk2;
        }
        __syncthreads();
        for (int i = t; i < lim; i += 256) {
            int bk2 = sbyte[i];
            int gp = gbase[bk2] + (i - lex[bk2]);
            if (gp < STRIDE) temp[(size_t)bk2 * STRIDE + gp] = (unsigned)sorted[i];
        }
    } else if (bid < nsp + nq) {
        // ---- Q GEMM: Qh = (x_node@Wq + bq)*qscale, f16 row-major ----
        int r0 = (bid - nsp) * 64;
        stage_w(Wt, Wl, t);
        int lane = t & 63, w = t >> 6;
        int lr = lane & 15, g = lane >> 4;
        f16x8 a[4];
        load_a_f32(x_node, r0 + 16 * w + lr, N, g, a);
        f32x4 acc[8];
#pragma unroll
        for (int i = 0; i < 8; ++i) acc[i] = (f32x4){0.f, 0.f, 0.f, 0.f};
        __syncthreads();
        mfma_ra(a, Wl, acc, lane);
        __syncthreads();
        // out tile (64x128 f16 = 16 KB) into Wl, swizzled at 8-half slots
#pragma unroll
        for (int ct = 0; ct < 8; ++ct) {
            int col = ct * 16 + lr;
            float bias = bq[col];
#pragma unroll
            for (int rg = 0; rg < 4; ++rg) {
                int row = 16 * w + 4 * g + rg;
                Wl[row * D + (((col >> 3) ^ (row & 15)) << 3) + (col & 7)] =
                    (f16)((acc[ct][rg] + bias) * qscale);
            }
        }
        __syncthreads();
#pragma unroll
        for (int i = 0; i < 4; ++i) {
            int f = t + i * 256;
            int r = f >> 4, c8 = f & 15;
            if (r0 + r < N) {
                uint4 v = *(const uint4*)(Wl + r * D + ((c8 ^ (r & 15)) << 3));
                *(uint4*)(Qh + (size_t)(r0 + r) * D + 8 * c8) = v;
            }
        }
    } else {
        // ---- K|V GEMM: KVh row = 32 chunks of (k[4]|v[4]) f16 ----
        int r0 = (bid - nsp - nq) * 64;
        stage_w(Wt + D * D, Wl, t);
        int lane = t & 63, w = t >> 6;
        int lr = lane & 15, g = lane >> 4;
        f16x8 a[4];
        load_a_f32(x_edge, r0 + 16 * w + lr, M, g, a);
        f32x4 accK[8], accV[8];
#pragma unroll
        for (int i = 0; i < 8; ++i) accK[i] = accV[i] = (f32x4){0.f, 0.f, 0.f, 0.f};
        __syncthreads();
        mfma_ra(a, Wl, accK, lane);
        __syncthreads();
        stage_w(Wt + 2 * D * D, Wl, t);
        __syncthreads();
        mfma_ra(a, Wl, accV, lane);
        __syncthreads();
        // interleaved KV tile (64x256 f16 = 32 KB) in Wl, swizzled at 8-half slots
#pragma unroll
        for (int ct = 0; ct < 8; ++ct) {
            int col = ct * 16 + lr;
            float bbk = bk[col], bbv = bv[col];
            int s = col >> 2, wk = col & 3;
#pragma unroll
            for (int rg = 0; rg < 4; ++rg) {
                int row = 16 * w + 4 * g + rg;
                f16* base = Wl + row * 256 + ((s ^ (row & 15)) << 3);
                base[wk] = (f16)(accK[ct][rg] + bbk);
                base[4 + wk] = (f16)(accV[ct][rg] + bbv);
            }
        }
        __syncthreads();
#pragma unroll
        for (int i = 0; i < 8; ++i) {
            int f = t + i * 256;
            int r = f >> 5, c8 = f & 31;
            if (r0 + r < M) {
                uint4 v = *(const uint4*)(Wl + r * 256 + ((c8 ^ (r & 15)) << 3));
                *(uint4*)(KVh + (size_t)(r0 + r) * 256 + 8 * c8) = v;
            }
        }
    }
}

// ---- bucket scatter v3: coarse dst-sort (counting sort by dst>>7) + node scatter ----
// Per-node lists come out approximately dst-ascending -> attention's KV window
// is a moving L2-resident slice. Any within-node order is numerically valid.
__global__ __launch_bounds__(256) void bucket_scatter(const unsigned* __restrict__ temp,
                                                      const int* __restrict__ bucket_cnt,
                                                      int* __restrict__ off,
                                                      int* __restrict__ csr_dst,
                                                      int N, int E, int NBUK) {
    __shared__ int nh[256], cur[256], wsum[4], sc_ex[256], dh[256], dcur[256];
    __shared__ int sorted2[STRIDE];
    __shared__ int lds_dst[STRIDE];
    int b = blockIdx.x, t = threadIdx.x;
    // scan 1: bucket counts -> sc_ex
    {
        int bc = (t < NBUK) ? bucket_cnt[t] : 0;
        int inc = bc;
#pragma unroll
        for (int m = 1; m < 64; m <<= 1) {
            int u = __shfl_up(inc, m);
            if ((t & 63) >= m) inc += u;
        }
        if ((t & 63) == 63) wsum[t >> 6] = inc;
        __syncthreads();
        int add = 0;
#pragma unroll
        for (int w = 0; w < 4; ++w)
            if (w < (t >> 6)) add += wsum[w];
        sc_ex[t] = add + inc - bc;
        nh[t] = 0;
        dh[t] = 0;
    }
    __syncthreads();
    int bo = sc_ex[b];
    int cnt = bucket_cnt[b];
    if (cnt > STRIDE) cnt = STRIDE;
    const unsigned* tb = temp + (size_t)b * STRIDE;
    // dst-coarse histogram (dst>>7 < 157)
    for (int i = t; i < cnt; i += 256) atomicAdd(&dh[(tb[i] & 0xFFFFFFu) >> 7], 1);
    __syncthreads();
    // scan 2: dh -> dcur (exclusive)
    {
        int v = dh[t];
        int inc = v;
#pragma unroll
        for (int m = 1; m < 64; m <<= 1) {
            int u = __shfl_up(inc, m);
            if ((t & 63) >= m) inc += u;
        }
        if ((t & 63) == 63) wsum[t >> 6] = inc;
        __syncthreads();
        int add = 0;
#pragma unroll
        for (int w = 0; w < 4; ++w)
            if (w < (t >> 6)) add += wsum[w];
        dcur[t] = add + inc - v;
    }
    __syncthreads();
    // dst-coarse scatter: sorted2 is dst-ascending (coarse)
    for (int i = t; i < cnt; i += 256) {
        unsigned it = tb[i];
        int pos = atomicAdd(&dcur[(it & 0xFFFFFFu) >> 7], 1);
        sorted2[pos] = (int)it;
    }
    __syncthreads();
    // node histogram over sorted2
    for (int i = t; i < cnt; i += 256) atomicAdd(&nh[((unsigned)sorted2[i]) >> 24], 1);
    __syncthreads();
    // scan 3: nh -> cur (exclusive); write off
    {
        int v = nh[t];
        int inc = v;
#pragma unroll
        for (int m = 1; m < 64; m <<= 1) {
            int u = __shfl_up(inc, m);
            if ((t & 63) >= m) inc += u;
        }
        if ((t & 63) == 63) wsum[t >> 6] = inc;
        __syncthreads();
        int add = 0;
#pragma unroll
        for (int w = 0; w < 4; ++w)
            if (w < (t >> 6)) add += wsum[w];
        int ex = add + inc - v;
        cur[t] = ex;
        int node = (b << 8) + t;
        if (node < N) off[node] = bo + ex;
        if (b == 0 && t == 0) off[N] = E;
    }
    __syncthreads();
    // node scatter (processing in sorted2 order -> per-node ~dst-ascending)
    for (int i = t; i < cnt; i += 256) {
        unsigned it = (unsigned)sorted2[i];
        int lpos = atomicAdd(&cur[it >> 24], 1);
        lds_dst[lpos] = (int)(it & 0xFFFFFFu);
    }
    __syncthreads();
    for (int i = t; i < cnt; i += 256) csr_dst[bo + i] = lds_dst[i];
}

// ---- fused per-node attention (R9-verified): 8 lanes/edge, 8 edges in flight ----
// Lane j owns dims 16j..16j+15; head = 32 dims = lane pair, reduce = shfl_xor(s,1) only.
__global__ __launch_bounds__(256) void node_attn4(const f16* __restrict__ Qh,
                                                  const f16* __restrict__ KVh,
                                                  const int* __restrict__ off,
                                                  const int* __restrict__ csr,
                                                  f16* __restrict__ aggh, int N) {
    int wid = (int)((blockIdx.x * (size_t)blockDim.x + threadIdx.x) >> 6);
    int lane = threadIdx.x & 63;
    if (wid >= N) return;
    int j = lane & 7, g = lane >> 3;
    const f16* qp = Qh + (size_t)wid * D + 16 * j;
    uint4 qA = *(const uint4*)qp;
    uint4 qB = *(const uint4*)(qp + 8);
    int beg = off[wid], end = off[wid + 1];
    float z = 0.f;
    f16x2 a0 = {0, 0}, a1 = {0, 0}, a2 = {0, 0}, a3 = {0, 0};
    f16x2 a4 = {0, 0}, a5 = {0, 0}, a6 = {0, 0}, a7 = {0, 0};
    if (beg < end) {
        int pe = beg + g;
        int d0 = csr[(pe < end) ? pe : end - 1];
        const f16* r = KVh + (size_t)d0 * 256 + 32 * j;
        uint4 A0 = *(const uint4*)r;
        uint4 A1 = *(const uint4*)(r + 8);
        uint4 A2 = *(const uint4*)(r + 16);
        uint4 A3 = *(const uint4*)(r + 24);
        for (int p = beg; p < end; p += 8) {
            int pn = p + 8 + g;
            int dn = csr[(pn < end) ? pn : end - 1];
            const f16* rn = KVh + (size_t)dn * 256 + 32 * j;
            uint4 B0 = *(const uint4*)rn;
            uint4 B1 = *(const uint4*)(rn + 8);
            uint4 B2 = *(const uint4*)(rn + 16);
            uint4 B3 = *(const uint4*)(rn + 24);
            bool valid = (p + g) < end;
            float s = dot2(A0.x, qA.x, 0.f);
            s = dot2(A0.y, qA.y, s);
            s = dot2(A1.x, qA.z, s);
            s = dot2(A1.y, qA.w, s);
            s = dot2(A2.x, qB.x, s);
            s = dot2(A2.y, qB.y, s);
            s = dot2(A3.x, qB.z, s);
            s = dot2(A3.y, qB.w, s);
            s += __shfl_xor(s, 1);   // lane pair = 32 dims = ONE head
            float eh = valid ? __expf(s) : 0.f;
            z += eh;
            f16 e16 = (f16)eh;
            f16x2 e2 = {e16, e16};
            a0 += e2 * u2h(A0.z); a1 += e2 * u2h(A0.w);
            a2 += e2 * u2h(A1.z); a3 += e2 * u2h(A1.w);
            a4 += e2 * u2h(A2.z); a5 += e2 * u2h(A2.w);
            a6 += e2 * u2h(A3.z); a7 += e2 * u2h(A3.w);
            A0 = B0; A1 = B1; A2 = B2; A3 = B3;
        }
    }
#pragma unroll
    for (int m = 8; m < 64; m <<= 1) {
        z += __shfl_xor(z, m);
        a0 += u2h(__shfl_xor((int)h2u(a0), m));
        a1 += u2h(__shfl_xor((int)h2u(a1), m));
        a2 += u2h(__shfl_xor((int)h2u(a2), m));
        a3 += u2h(__shfl_xor((int)h2u(a3), m));
        a4 += u2h(__shfl_xor((int)h2u(a4), m));
        a5 += u2h(__shfl_xor((int)h2u(a5), m));
        a6 += u2h(__shfl_xor((int)h2u(a6), m));
        a7 += u2h(__shfl_xor((int)h2u(a7), m));
    }
    if (g == 0) {
        float inv = (end > beg) ? 1.f / z : 0.f;
        uint4 o0, o1;
        o0.x = h2u((f16x2){(f16)((float)a0.x * inv), (f16)((float)a0.y * inv)});
        o0.y = h2u((f16x2){(f16)((float)a1.x * inv), (f16)((float)a1.y * inv)});
        o0.z = h2u((f16x2){(f16)((float)a2.x * inv), (f16)((float)a2.y * inv)});
        o0.w = h2u((f16x2){(f16)((float)a3.x * inv), (f16)((float)a3.y * inv)});
        o1.x = h2u((f16x2){(f16)((float)a4.x * inv), (f16)((float)a4.y * inv)});
        o1.y = h2u((f16x2){(f16)((float)a5.x * inv), (f16)((float)a5.y * inv)});
        o1.z = h2u((f16x2){(f16)((float)a6.x * inv), (f16)((float)a6.y * inv)});
        o1.w = h2u((f16x2){(f16)((float)a7.x * inv), (f16)((float)a7.y * inv)});
        f16* op = aggh + (size_t)wid * D + 16 * j;
        *(uint4*)op = o0;
        *(uint4*)(op + 8) = o1;
    }
}

// ---- out GEMM: d_out = aggh(f16) @ Wo + bo + x_node, fp32 out; A direct from global ----
__global__ __launch_bounds__(256) void gemm_o(const f16* __restrict__ aggh,
                                              const f16* __restrict__ Wt,
                                              const float* __restrict__ b,
                                              const float* __restrict__ resid,
                                              float* __restrict__ y, int nrows) {
    __shared__ __align__(16) f16 Wl[D * D];   // 32 KB (reused as fp32 out tile)
    int t = threadIdx.x;
    int r0 = blockIdx.x * 64;
    stage_w(Wt, Wl, t);
    int lane = t & 63, w = t >> 6;
    int lr = lane & 15, g = lane >> 4;
    int gr = r0 + 16 * w + lr;
    f16x8 a[4];
#pragma unroll
    for (int kc = 0; kc < 4; ++kc) {
        uint4 v = {0u, 0u, 0u, 0u};
        if (gr < nrows) v = *(const uint4*)(aggh + (size_t)gr * D + (kc * 4 + g) * 8);
        a[kc] = __builtin_bit_cast(f16x8, v);
    }
    f32x4 acc[8];
#pragma unroll
    for (int i = 0; i < 8; ++i) acc[i] = (f32x4){0.f, 0.f, 0.f, 0.f};
    __syncthreads();
    mfma_ra(a, Wl, acc, lane);
    __syncthreads();
    float* Tf = (float*)Wl;   // 64x128 fp32 = 32 KB, swizzled at 4-float slots
#pragma unroll
    for (int ct = 0; ct < 8; ++ct) {
        int col = ct * 16 + lr;
        float bias = b[col];
        int s = col >> 2, wk = col & 3;
#pragma unroll
        for (int rg = 0; rg < 4; ++rg) {
            int row = 16 * w + 4 * g + rg;
            Tf[row * D + ((s ^ (row & 15)) << 2) + wk] = acc[ct][rg] + bias;
        }
    }
    __syncthreads();
#pragma unroll
    for (int i = 0; i < 8; ++i) {
        int f = t + i * 256;
        int r = f >> 5, c4 = f & 31;
        int gr2 = r0 + r;
        if (gr2 < nrows) {
            float4 v = *(const float4*)(Tf + r * D + ((c4 ^ (r & 15)) << 2));
            float4 rv = *(const float4*)(resid + (size_t)gr2 * D + 4 * c4);
            v.x += rv.x; v.y += rv.y; v.z += rv.z; v.w += rv.w;
            *(float4*)(y + (size_t)gr2 * D + 4 * c4) = v;
        }
    }
}

extern "C" void kernel_launch(void* const* d_in, const int* in_sizes, int n_in,
                              void* d_out, int out_size, void* d_ws, size_t ws_size,
                              hipStream_t stream) {
    const float* x_node = (const float*)d_in[0];
    const float* x_edge = (const float*)d_in[1];
    const int* src = (const int*)d_in[2];
    const int* dst = (const int*)d_in[3];
    const float* Wq = (const float*)d_in[4];
    const float* bq = (const float*)d_in[5];
    const float* Wk = (const float*)d_in[6];
    const float* bk = (const float*)d_in[7];
    const float* Wv = (const float*)d_in[8];
    const float* bv = (const float*)d_in[9];
    const float* Wo = (const float*)d_in[10];
    const float* bo = (const float*)d_in[11];

    int N = in_sizes[0] / D;   // 50000
    int M = in_sizes[1] / D;   // 20000
    int E = in_sizes[2];       // 800000
    int NBUK = (N + 255) >> 8; // 196

    char* p = (char*)d_ws;
    auto alloc = [&](size_t bytes) -> char* {
        char* r = p;
        p += (bytes + 15) & ~(size_t)15;
        return r;
    };
    f16* Wt = (f16*)alloc((size_t)4 * D * D * 2);      // q,k,v,o swizzled images
    f16* Qh = (f16*)alloc((size_t)N * D * 2);
    f16* KVh = (f16*)alloc((size_t)M * 256 * 2);
    f16* aggh = (f16*)alloc((size_t)N * D * 2);
    int* bucket_cnt = (int*)alloc(256 * 4);
    int* off = (int*)alloc((size_t)(N + 1) * 4);
    unsigned* temp = (unsigned*)alloc((size_t)NBUK * STRIDE * 4);
    int* csr_dst = (int*)alloc((size_t)E * 4);
    float* out = (float*)d_out;

    hipMemsetAsync(bucket_cnt, 0, 256 * 4, stream);

    wt_prep4<<<4, 256, 0, stream>>>(Wq, Wk, Wv, Wo, Wt);

    int nq = (N + 63) / 64;      // 782
    int nkv = (M + 63) / 64;     // 313
    int nsp = (E + 4095) / 4096; // 196
    fused_front<<<nsp + nq + nkv, 256, 0, stream>>>(x_node, x_edge, src, dst, Wt,
                                                    bq, bk, bv, Qh, KVh,
                                                    bucket_cnt, temp,
                                                    N, M, E, nsp, nq, 0.17677669529663687f);

    bucket_scatter<<<NBUK, 256, 0, stream>>>(temp, bucket_cnt, off, csr_dst, N, E, NBUK);

    int ablk = (int)(((size_t)N * 64 + 255) / 256);
    node_attn4<<<ablk, 256, 0, stream>>>(Qh, KVh, off, csr_dst, aggh, N);

    gemm_o<<<(N + 63) / 64, 256, 0, stream>>>(aggh, Wt + 3 * D * D, bo, x_node, out, N);
}

// Round 17
// 107.568 us; speedup vs baseline: 1.4687x; 1.0602x over previous
//
#include <hip/hip_runtime.h>

#define D 128
#define STRIDE 6144  // max edges per 256-node bucket (mean 4082, sd 64)

typedef _Float16 f16;
typedef f16 f16x2 __attribute__((ext_vector_type(2)));
typedef f16 f16x8 __attribute__((ext_vector_type(8)));
typedef float f32x4 __attribute__((ext_vector_type(4)));

__device__ inline f16x2 u2h(unsigned u) { return __builtin_bit_cast(f16x2, u); }
__device__ inline unsigned h2u(f16x2 h) { return __builtin_bit_cast(unsigned, h); }

__device__ inline float dot2(unsigned a, unsigned b, float c) {
#if __has_builtin(__builtin_amdgcn_fdot2)
    return __builtin_amdgcn_fdot2(u2h(a), u2h(b), c, false);
#else
    f16x2 x = u2h(a), y = u2h(b);
    return c + (float)x.x * (float)y.x + (float)x.y * (float)y.y;
#endif
}

// ---- kernel 1: [wt_prep (bid 0..3) | bucket_split (bid 4..)] ----
// wt_prep: W fp32 -> transposed f16 swizzled image. f16 idx (col c, k):
//   c*128 + ((k>>3) ^ (c&15))*8 + (k&7)
__global__ __launch_bounds__(256) void prep_split(
    const float* __restrict__ Wq, const float* __restrict__ Wk,
    const float* __restrict__ Wv, const float* __restrict__ Wo,
    const int* __restrict__ src, const int* __restrict__ dst,
    f16* __restrict__ Wt, int* __restrict__ bucket_cnt, unsigned* __restrict__ temp, int E) {
    __shared__ __align__(16) int smem[6400 + 1024];  // 25 KB+ for split branch
    int t = threadIdx.x;
    int bid = blockIdx.x;
    if (bid < 4) {
        const float* W = (bid == 0) ? Wq : (bid == 1) ? Wk : (bid == 2) ? Wv : Wo;
        f16* o = Wt + (size_t)bid * D * D;
#pragma unroll
        for (int i = 0; i < 16; ++i) {
            int f = t + i * 256;
            int k = f >> 5, c4 = f & 31;
            float4 v = *(const float4*)(W + k * D + 4 * c4);
            float vv[4] = {v.x, v.y, v.z, v.w};
#pragma unroll
            for (int e = 0; e < 4; ++e) {
                int c = 4 * c4 + e;
                o[c * D + (((k >> 3) ^ (c & 15)) << 3) + (k & 7)] = (f16)vv[e];
            }
        }
    } else {
        // bucket split: LDS bucket-sort, coalesced run-writes to temp
        int* hist = smem;                 // 256
        int* lex = hist + 256;            // 256
        int* gbase = lex + 256;           // 256
        int* lcur = gbase + 256;          // 256
        int* wsum = lcur + 256;           // 16
        int* sorted = wsum + 16;          // 4096
        unsigned char* sbyte = (unsigned char*)(sorted + 4096);  // 4096 B
        hist[t] = 0;
        lcur[t] = 0;
        __syncthreads();
        int base0 = (bid - 4) * 4096;
        int lim = E - base0; if (lim > 4096) lim = 4096;
        for (int i = t; i < lim; i += 256) atomicAdd(&hist[src[base0 + i] >> 8], 1);
        __syncthreads();
        int v = hist[t];
        int inc = v;
#pragma unroll
        for (int m = 1; m < 64; m <<= 1) {
            int u = __shfl_up(inc, m);
            if ((t & 63) >= m) inc += u;
        }
        if ((t & 63) == 63) wsum[t >> 6] = inc;
        __syncthreads();
        int add = 0;
#pragma unroll
        for (int w = 0; w < 4; ++w)
            if (w < (t >> 6)) add += wsum[w];
        lex[t] = add + inc - v;
        if (v) gbase[t] = atomicAdd(&bucket_cnt[t], v);
        __syncthreads();
        for (int i = t; i < lim; i += 256) {
            int s = src[base0 + i];
            int bk2 = s >> 8;
            int lp = atomicAdd(&lcur[bk2], 1);
            int sp = lex[bk2] + lp;
            sorted[sp] = ((s & 255) << 24) | dst[base0 + i];
            sbyte[sp] = (unsigned char)bk2;
        }
        __syncthreads();
        for (int i = t; i < lim; i += 256) {
            int bk2 = sbyte[i];
            int gp = gbase[bk2] + (i - lex[bk2]);
            if (gp < STRIDE) temp[(size_t)bk2 * STRIDE + gp] = (unsigned)sorted[i];
        }
    }
}

// ---- shared GEMM pieces ----
__device__ inline void stage_w(const f16* __restrict__ Wt, f16* Wl, int t) {
#pragma unroll
    for (int i = 0; i < 8; ++i) ((uint4*)Wl)[t + i * 256] = ((const uint4*)Wt)[t + i * 256];
}

__device__ inline void load_a_f32(const float* __restrict__ x, int gr, int nrows, int g,
                                  f16x8 a[4]) {
#pragma unroll
    for (int kc = 0; kc < 4; ++kc) {
        float4 v0 = {0.f, 0.f, 0.f, 0.f}, v1 = {0.f, 0.f, 0.f, 0.f};
        if (gr < nrows) {
            const float* xr = x + (size_t)gr * D + (kc * 4 + g) * 8;
            v0 = *(const float4*)xr;
            v1 = *(const float4*)(xr + 4);
        }
        f16x8 af;
        af[0] = (f16)v0.x; af[1] = (f16)v0.y; af[2] = (f16)v0.z; af[3] = (f16)v0.w;
        af[4] = (f16)v1.x; af[5] = (f16)v1.y; af[6] = (f16)v1.z; af[7] = (f16)v1.w;
        a[kc] = af;
    }
}

__device__ inline void mfma_ra(const f16x8 a[4], const f16* Wl, f32x4 acc[8], int lane) {
    int lr = lane & 15, g = lane >> 4;
#pragma unroll
    for (int kc = 0; kc < 4; ++kc) {
        int slot = kc * 4 + g;
#pragma unroll
        for (int ct = 0; ct < 8; ++ct) {
            int col = ct * 16 + lr;
            f16x8 bf = *(const f16x8*)(Wl + col * D + ((slot ^ (col & 15)) << 3));
            acc[ct] = __builtin_amdgcn_mfma_f32_16x16x32_f16(a[kc], bf, acc[ct], 0, 0, 0);
        }
    }
}

// ---- kernel 2: [bucket_scatter (bid 0..195) | gemm_q | gemm_kv] ----
// Scatter depends only on kernel 1 (split done); hides under GEMM blocks.
// LDS = 32 KB shared region for all branches.
__global__ __launch_bounds__(256) void fused_front(
    const float* __restrict__ x_node, const float* __restrict__ x_edge,
    const f16* __restrict__ Wt,
    const float* __restrict__ bq, const float* __restrict__ bk, const float* __restrict__ bv,
    f16* __restrict__ Qh, f16* __restrict__ KVh,
    const unsigned* __restrict__ temp, const int* __restrict__ bucket_cnt,
    int* __restrict__ off, int* __restrict__ csr_dst,
    int N, int M, int E, int nsc, int nq, int NBUK, float qscale) {
    __shared__ __align__(16) f16 Wl[D * D];     // 32 KB shared scratch
    int t = threadIdx.x;
    int bid = blockIdx.x;

    if (bid < nsc) {
        // ---- scatter-lite: counters (5 KB) + sorted2 (24 KB) in Wl region ----
        int* nh = (int*)Wl;          // 256
        int* cur = nh + 256;         // 256
        int* wsum = cur + 256;       // 16
        int* sc_ex = wsum + 16;      // 256
        int* dh = sc_ex + 256;       // 256
        int* dcur = dh + 256;        // 256
        int* sorted2 = dcur + 256;   // 6144 -> total 29.2 KB
        int b = bid;
        // scan 1: bucket counts -> sc_ex
        {
            int bc = (t < NBUK) ? bucket_cnt[t] : 0;
            int inc = bc;
#pragma unroll
            for (int m = 1; m < 64; m <<= 1) {
                int u = __shfl_up(inc, m);
                if ((t & 63) >= m) inc += u;
            }
            if ((t & 63) == 63) wsum[t >> 6] = inc;
            __syncthreads();
            int add = 0;
#pragma unroll
            for (int w = 0; w < 4; ++w)
                if (w < (t >> 6)) add += wsum[w];
            sc_ex[t] = add + inc - bc;
            nh[t] = 0;
            dh[t] = 0;
        }
        __syncthreads();
        int bo = sc_ex[b];
        int cnt = bucket_cnt[b];
        if (cnt > STRIDE) cnt = STRIDE;
        const unsigned* tb = temp + (size_t)b * STRIDE;
        for (int i = t; i < cnt; i += 256) atomicAdd(&dh[(tb[i] & 0xFFFFFFu) >> 7], 1);
        __syncthreads();
        {
            int v = dh[t];
            int inc = v;
#pragma unroll
            for (int m = 1; m < 64; m <<= 1) {
                int u = __shfl_up(inc, m);
                if ((t & 63) >= m) inc += u;
            }
            if ((t & 63) == 63) wsum[t >> 6] = inc;
            __syncthreads();
            int add = 0;
#pragma unroll
            for (int w = 0; w < 4; ++w)
                if (w < (t >> 6)) add += wsum[w];
            dcur[t] = add + inc - v;
        }
        __syncthreads();
        for (int i = t; i < cnt; i += 256) {
            unsigned it = tb[i];
            int pos = atomicAdd(&dcur[(it & 0xFFFFFFu) >> 7], 1);
            sorted2[pos] = (int)it;
        }
        __syncthreads();
        for (int i = t; i < cnt; i += 256) atomicAdd(&nh[((unsigned)sorted2[i]) >> 24], 1);
        __syncthreads();
        {
            int v = nh[t];
            int inc = v;
#pragma unroll
            for (int m = 1; m < 64; m <<= 1) {
                int u = __shfl_up(inc, m);
                if ((t & 63) >= m) inc += u;
            }
            if ((t & 63) == 63) wsum[t >> 6] = inc;
            __syncthreads();
            int add = 0;
#pragma unroll
            for (int w = 0; w < 4; ++w)
                if (w < (t >> 6)) add += wsum[w];
            int ex = add + inc - v;
            cur[t] = ex;
            int node = (b << 8) + t;
            if (node < N) off[node] = bo + ex;
            if (b == 0 && t == 0) off[N] = E;
        }
        __syncthreads();
        // direct scattered csr write (dst-ascending processing preserves coarse sort)
        for (int i = t; i < cnt; i += 256) {
            unsigned it = (unsigned)sorted2[i];
            int lpos = atomicAdd(&cur[it >> 24], 1);
            csr_dst[bo + lpos] = (int)(it & 0xFFFFFFu);
        }
    } else if (bid < nsc + nq) {
        // ---- Q GEMM: Qh = (x_node@Wq + bq)*qscale, f16 row-major ----
        int r0 = (bid - nsc) * 64;
        stage_w(Wt, Wl, t);
        int lane = t & 63, w = t >> 6;
        int lr = lane & 15, g = lane >> 4;
        f16x8 a[4];
        load_a_f32(x_node, r0 + 16 * w + lr, N, g, a);
        f32x4 acc[8];
#pragma unroll
        for (int i = 0; i < 8; ++i) acc[i] = (f32x4){0.f, 0.f, 0.f, 0.f};
        __syncthreads();
        mfma_ra(a, Wl, acc, lane);
        __syncthreads();
#pragma unroll
        for (int ct = 0; ct < 8; ++ct) {
            int col = ct * 16 + lr;
            float bias = bq[col];
#pragma unroll
            for (int rg = 0; rg < 4; ++rg) {
                int row = 16 * w + 4 * g + rg;
                Wl[row * D + (((col >> 3) ^ (row & 15)) << 3) + (col & 7)] =
                    (f16)((acc[ct][rg] + bias) * qscale);
            }
        }
        __syncthreads();
#pragma unroll
        for (int i = 0; i < 4; ++i) {
            int f = t + i * 256;
            int r = f >> 4, c8 = f & 15;
            if (r0 + r < N) {
                uint4 v = *(const uint4*)(Wl + r * D + ((c8 ^ (r & 15)) << 3));
                *(uint4*)(Qh + (size_t)(r0 + r) * D + 8 * c8) = v;
            }
        }
    } else {
        // ---- K|V GEMM: KVh row = 32 chunks of (k[4]|v[4]) f16 ----
        int r0 = (bid - nsc - nq) * 64;
        stage_w(Wt + D * D, Wl, t);
        int lane = t & 63, w = t >> 6;
        int lr = lane & 15, g = lane >> 4;
        f16x8 a[4];
        load_a_f32(x_edge, r0 + 16 * w + lr, M, g, a);
        f32x4 accK[8], accV[8];
#pragma unroll
        for (int i = 0; i < 8; ++i) accK[i] = accV[i] = (f32x4){0.f, 0.f, 0.f, 0.f};
        __syncthreads();
        mfma_ra(a, Wl, accK, lane);
        __syncthreads();
        stage_w(Wt + 2 * D * D, Wl, t);
        __syncthreads();
        mfma_ra(a, Wl, accV, lane);
        __syncthreads();
#pragma unroll
        for (int ct = 0; ct < 8; ++ct) {
            int col = ct * 16 + lr;
            float bbk = bk[col], bbv = bv[col];
            int s = col >> 2, wk = col & 3;
#pragma unroll
            for (int rg = 0; rg < 4; ++rg) {
                int row = 16 * w + 4 * g + rg;
                f16* base = Wl + row * 256 + ((s ^ (row & 15)) << 3);
                base[wk] = (f16)(accK[ct][rg] + bbk);
                base[4 + wk] = (f16)(accV[ct][rg] + bbv);
            }
        }
        __syncthreads();
#pragma unroll
        for (int i = 0; i < 8; ++i) {
            int f = t + i * 256;
            int r = f >> 5, c8 = f & 31;
            if (r0 + r < M) {
                uint4 v = *(const uint4*)(Wl + r * 256 + ((c8 ^ (r & 15)) << 3));
                *(uint4*)(KVh + (size_t)(r0 + r) * 256 + 8 * c8) = v;
            }
        }
    }
}

// ---- fused per-node attention (R9-verified): 8 lanes/edge, 8 edges in flight ----
__global__ __launch_bounds__(256) void node_attn4(const f16* __restrict__ Qh,
                                                  const f16* __restrict__ KVh,
                                                  const int* __restrict__ off,
                                                  const int* __restrict__ csr,
                                                  f16* __restrict__ aggh, int N) {
    int wid = (int)((blockIdx.x * (size_t)blockDim.x + threadIdx.x) >> 6);
    int lane = threadIdx.x & 63;
    if (wid >= N) return;
    int j = lane & 7, g = lane >> 3;
    const f16* qp = Qh + (size_t)wid * D + 16 * j;
    uint4 qA = *(const uint4*)qp;
    uint4 qB = *(const uint4*)(qp + 8);
    int beg = off[wid], end = off[wid + 1];
    float z = 0.f;
    f16x2 a0 = {0, 0}, a1 = {0, 0}, a2 = {0, 0}, a3 = {0, 0};
    f16x2 a4 = {0, 0}, a5 = {0, 0}, a6 = {0, 0}, a7 = {0, 0};
    if (beg < end) {
        int pe = beg + g;
        int d0 = csr[(pe < end) ? pe : end - 1];
        const f16* r = KVh + (size_t)d0 * 256 + 32 * j;
        uint4 A0 = *(const uint4*)r;
        uint4 A1 = *(const uint4*)(r + 8);
        uint4 A2 = *(const uint4*)(r + 16);
        uint4 A3 = *(const uint4*)(r + 24);
        for (int p = beg; p < end; p += 8) {
            int pn = p + 8 + g;
            int dn = csr[(pn < end) ? pn : end - 1];
            const f16* rn = KVh + (size_t)dn * 256 + 32 * j;
            uint4 B0 = *(const uint4*)rn;
            uint4 B1 = *(const uint4*)(rn + 8);
            uint4 B2 = *(const uint4*)(rn + 16);
            uint4 B3 = *(const uint4*)(rn + 24);
            bool valid = (p + g) < end;
            float s = dot2(A0.x, qA.x, 0.f);
            s = dot2(A0.y, qA.y, s);
            s = dot2(A1.x, qA.z, s);
            s = dot2(A1.y, qA.w, s);
            s = dot2(A2.x, qB.x, s);
            s = dot2(A2.y, qB.y, s);
            s = dot2(A3.x, qB.z, s);
            s = dot2(A3.y, qB.w, s);
            s += __shfl_xor(s, 1);   // lane pair = 32 dims = ONE head
            float eh = valid ? __expf(s) : 0.f;
            z += eh;
            f16 e16 = (f16)eh;
            f16x2 e2 = {e16, e16};
            a0 += e2 * u2h(A0.z); a1 += e2 * u2h(A0.w);
            a2 += e2 * u2h(A1.z); a3 += e2 * u2h(A1.w);
            a4 += e2 * u2h(A2.z); a5 += e2 * u2h(A2.w);
            a6 += e2 * u2h(A3.z); a7 += e2 * u2h(A3.w);
            A0 = B0; A1 = B1; A2 = B2; A3 = B3;
        }
    }
#pragma unroll
    for (int m = 8; m < 64; m <<= 1) {
        z += __shfl_xor(z, m);
        a0 += u2h(__shfl_xor((int)h2u(a0), m));
        a1 += u2h(__shfl_xor((int)h2u(a1), m));
        a2 += u2h(__shfl_xor((int)h2u(a2), m));
        a3 += u2h(__shfl_xor((int)h2u(a3), m));
        a4 += u2h(__shfl_xor((int)h2u(a4), m));
        a5 += u2h(__shfl_xor((int)h2u(a5), m));
        a6 += u2h(__shfl_xor((int)h2u(a6), m));
        a7 += u2h(__shfl_xor((int)h2u(a7), m));
    }
    if (g == 0) {
        float inv = (end > beg) ? 1.f / z : 0.f;
        uint4 o0, o1;
        o0.x = h2u((f16x2){(f16)((float)a0.x * inv), (f16)((float)a0.y * inv)});
        o0.y = h2u((f16x2){(f16)((float)a1.x * inv), (f16)((float)a1.y * inv)});
        o0.z = h2u((f16x2){(f16)((float)a2.x * inv), (f16)((float)a2.y * inv)});
        o0.w = h2u((f16x2){(f16)((float)a3.x * inv), (f16)((float)a3.y * inv)});
        o1.x = h2u((f16x2){(f16)((float)a4.x * inv), (f16)((float)a4.y * inv)});
        o1.y = h2u((f16x2){(f16)((float)a5.x * inv), (f16)((float)a5.y * inv)});
        o1.z = h2u((f16x2){(f16)((float)a6.x * inv), (f16)((float)a6.y * inv)});
        o1.w = h2u((f16x2){(f16)((float)a7.x * inv), (f16)((float)a7.y * inv)});
        f16* op = aggh + (size_t)wid * D + 16 * j;
        *(uint4*)op = o0;
        *(uint4*)(op + 8) = o1;
    }
}

// ---- out GEMM: d_out = aggh(f16) @ Wo + bo + x_node, fp32 out; A direct from global ----
__global__ __launch_bounds__(256) void gemm_o(const f16* __restrict__ aggh,
                                              const f16* __restrict__ Wt,
                                              const float* __restrict__ b,
                                              const float* __restrict__ resid,
                                              float* __restrict__ y, int nrows) {
    __shared__ __align__(16) f16 Wl[D * D];
    int t = threadIdx.x;
    int r0 = blockIdx.x * 64;
    stage_w(Wt, Wl, t);
    int lane = t & 63, w = t >> 6;
    int lr = lane & 15, g = lane >> 4;
    int gr = r0 + 16 * w + lr;
    f16x8 a[4];
#pragma unroll
    for (int kc = 0; kc < 4; ++kc) {
        uint4 v = {0u, 0u, 0u, 0u};
        if (gr < nrows) v = *(const uint4*)(aggh + (size_t)gr * D + (kc * 4 + g) * 8);
        a[kc] = __builtin_bit_cast(f16x8, v);
    }
    f32x4 acc[8];
#pragma unroll
    for (int i = 0; i < 8; ++i) acc[i] = (f32x4){0.f, 0.f, 0.f, 0.f};
    __syncthreads();
    mfma_ra(a, Wl, acc, lane);
    __syncthreads();
    float* Tf = (float*)Wl;
#pragma unroll
    for (int ct = 0; ct < 8; ++ct) {
        int col = ct * 16 + lr;
        float bias = b[col];
        int s = col >> 2, wk = col & 3;
#pragma unroll
        for (int rg = 0; rg < 4; ++rg) {
            int row = 16 * w + 4 * g + rg;
            Tf[row * D + ((s ^ (row & 15)) << 2) + wk] = acc[ct][rg] + bias;
        }
    }
    __syncthreads();
#pragma unroll
    for (int i = 0; i < 8; ++i) {
        int f = t + i * 256;
        int r = f >> 5, c4 = f & 31;
        int gr2 = r0 + r;
        if (gr2 < nrows) {
            float4 v = *(const float4*)(Tf + r * D + ((c4 ^ (r & 15)) << 2));
            float4 rv = *(const float4*)(resid + (size_t)gr2 * D + 4 * c4);
            v.x += rv.x; v.y += rv.y; v.z += rv.z; v.w += rv.w;
            *(float4*)(y + (size_t)gr2 * D + 4 * c4) = v;
        }
    }
}

extern "C" void kernel_launch(void* const* d_in, const int* in_sizes, int n_in,
                              void* d_out, int out_size, void* d_ws, size_t ws_size,
                              hipStream_t stream) {
    const float* x_node = (const float*)d_in[0];
    const float* x_edge = (const float*)d_in[1];
    const int* src = (const int*)d_in[2];
    const int* dst = (const int*)d_in[3];
    const float* Wq = (const float*)d_in[4];
    const float* bq = (const float*)d_in[5];
    const float* Wk = (const float*)d_in[6];
    const float* bk = (const float*)d_in[7];
    const float* Wv = (const float*)d_in[8];
    const float* bv = (const float*)d_in[9];
    const float* Wo = (const float*)d_in[10];
    const float* bo = (const float*)d_in[11];

    int N = in_sizes[0] / D;   // 50000
    int M = in_sizes[1] / D;   // 20000
    int E = in_sizes[2];       // 800000
    int NBUK = (N + 255) >> 8; // 196

    char* p = (char*)d_ws;
    auto alloc = [&](size_t bytes) -> char* {
        char* r = p;
        p += (bytes + 15) & ~(size_t)15;
        return r;
    };
    f16* Wt = (f16*)alloc((size_t)4 * D * D * 2);      // q,k,v,o swizzled images
    f16* Qh = (f16*)alloc((size_t)N * D * 2);
    f16* KVh = (f16*)alloc((size_t)M * 256 * 2);
    f16* aggh = (f16*)alloc((size_t)N * D * 2);
    int* bucket_cnt = (int*)alloc(256 * 4);
    int* off = (int*)alloc((size_t)(N + 1) * 4);
    unsigned* temp = (unsigned*)alloc((size_t)NBUK * STRIDE * 4);
    int* csr_dst = (int*)alloc((size_t)E * 4);
    float* out = (float*)d_out;

    hipMemsetAsync(bucket_cnt, 0, 256 * 4, stream);

    int nsp = (E + 4095) / 4096; // 196
    int nq = (N + 63) / 64;      // 782
    int nkv = (M + 63) / 64;     // 313

    // kernel 1: wt_prep (4 blocks) + bucket_split (196 blocks)
    prep_split<<<4 + nsp, 256, 0, stream>>>(Wq, Wk, Wv, Wo, src, dst,
                                            Wt, bucket_cnt, temp, E);

    // kernel 2: scatter (196) | Q GEMM (782) | KV GEMM (313)
    fused_front<<<NBUK + nq + nkv, 256, 0, stream>>>(x_node, x_edge, Wt,
                                                     bq, bk, bv, Qh, KVh,
                                                     temp, bucket_cnt, off, csr_dst,
                                                     N, M, E, NBUK, nq, NBUK,
                                                     0.17677669529663687f);

    int ablk = (int)(((size_t)N * 64 + 255) / 256);
    node_attn4<<<ablk, 256, 0, stream>>>(Qh, KVh, off, csr_dst, aggh, N);

    gemm_o<<<(N + 63) / 64, 256, 0, stream>>>(aggh, Wt + 3 * D * D, bo, x_node, out, N);
}